// Round 9
// baseline (604.334 us; speedup 1.0000x reference)
//
#include <hip/hip_runtime.h>

// Problem constants
#define BB 16
#define NN 1024
#define FIN 64
#define FOUT 128
#define DD 64
#define HH 4
#define NEG 0.2f

#define RT 32     // rows per block in K1
#define RT2 16    // rows per block in K2
#define CT 128    // column tile in K2

typedef __attribute__((ext_vector_type(8))) short short8;
typedef __attribute__((ext_vector_type(4))) float f32x4;

__device__ __forceinline__ unsigned short f2bf(float x) {
    union { float f; unsigned u; } v; v.f = x;
    unsigned r = v.u + 0x7fffu + ((v.u >> 16) & 1u);
    return (unsigned short)(r >> 16);
}
__device__ __forceinline__ float bf2f(unsigned short s) {
    union { float f; unsigned u; } v; v.u = ((unsigned)s) << 16;
    return v.f;
}
__device__ __forceinline__ unsigned pack2bf(float lo, float hi) {
    return (unsigned)f2bf(lo) | ((unsigned)f2bf(hi) << 16);
}

#define MFMA(a, b, c) __builtin_amdgcn_mfma_f32_16x16x32_bf16((a), (b), (c), 0, 0, 0)

// ---------------- Kernel 1: h_prime (bf16 fragment-packed), attn_src/dst (bf16 hi/lo), hp_sum ----------------
__global__ __launch_bounds__(256) void gat_k1(
    const float* __restrict__ h,      // [B,N,FIN]
    const float* __restrict__ w,      // [H,FIN,FOUT]
    const float* __restrict__ a_src,  // [H,FOUT,DD]
    const float* __restrict__ a_dst,  // [H,FOUT,DD]
    unsigned short* __restrict__ asHg,  // [B,H,N,DD] bf16 hi
    unsigned short* __restrict__ asLg,  // lo
    unsigned short* __restrict__ adHg,
    unsigned short* __restrict__ adLg,
    unsigned short* __restrict__ hpPg,  // [B*H][N/32][FOUT][32] bf16 fragment-packed h'
    float* __restrict__ hpsum)          // [B,N,FOUT]
{
    __shared__ float hL[RT][FIN + 1];      // 32x65
    __shared__ float wL[FIN][FOUT + 2];    // 64x130
    __shared__ float hpL[RT][FOUT + 2];    // 32x130

    const int t  = threadIdx.x;
    const int tx = t & 31;
    const int ty = t >> 5;           // 0..7
    const int blk = blockIdx.x;
    const int b   = blk / (NN / RT);
    const int n0  = (blk % (NN / RT)) * RT;

    for (int idx = t; idx < RT * FIN / 4; idx += 256) {
        int r = (idx * 4) / FIN;
        int f = (idx * 4) % FIN;
        float4 v = *reinterpret_cast<const float4*>(&h[((size_t)b * NN + n0 + r) * FIN + f]);
        hL[r][f + 0] = v.x; hL[r][f + 1] = v.y; hL[r][f + 2] = v.z; hL[r][f + 3] = v.w;
    }

    float sum_acc[4][4];
#pragma unroll
    for (int i = 0; i < 4; i++)
#pragma unroll
        for (int j = 0; j < 4; j++) sum_acc[i][j] = 0.f;

    for (int hh = 0; hh < HH; ++hh) {
        __syncthreads();
        for (int idx = t; idx < FIN * FOUT / 4; idx += 256) {
            int k = (idx * 4) / FOUT;
            int o = (idx * 4) % FOUT;
            float4 v = *reinterpret_cast<const float4*>(&w[((size_t)hh * FIN + k) * FOUT + o]);
            wL[k][o + 0] = v.x; wL[k][o + 1] = v.y; wL[k][o + 2] = v.z; wL[k][o + 3] = v.w;
        }
        __syncthreads();

        float acc[4][4];
#pragma unroll
        for (int i = 0; i < 4; i++)
#pragma unroll
            for (int j = 0; j < 4; j++) acc[i][j] = 0.f;

#pragma unroll 8
        for (int k = 0; k < FIN; k++) {
            float av0 = hL[ty][k], av1 = hL[ty + 8][k], av2 = hL[ty + 16][k], av3 = hL[ty + 24][k];
            float bv0 = wL[k][tx], bv1 = wL[k][tx + 32], bv2 = wL[k][tx + 64], bv3 = wL[k][tx + 96];
            acc[0][0] += av0 * bv0; acc[0][1] += av0 * bv1; acc[0][2] += av0 * bv2; acc[0][3] += av0 * bv3;
            acc[1][0] += av1 * bv0; acc[1][1] += av1 * bv1; acc[1][2] += av1 * bv2; acc[1][3] += av1 * bv3;
            acc[2][0] += av2 * bv0; acc[2][1] += av2 * bv1; acc[2][2] += av2 * bv2; acc[2][3] += av2 * bv3;
            acc[3][0] += av3 * bv0; acc[3][1] += av3 * bv1; acc[3][2] += av3 * bv2; acc[3][3] += av3 * bv3;
        }

        const size_t bh = (size_t)b * HH + hh;
#pragma unroll
        for (int i = 0; i < 4; i++) {
            int r = i * 8 + ty;
#pragma unroll
            for (int j = 0; j < 4; j++) {
                int o = j * 32 + tx;
                hpL[r][o] = acc[i][j];
                sum_acc[i][j] += acc[i][j];
            }
        }
        __syncthreads();

        float as0[4], as1[4], ad0[4], ad1[4];
#pragma unroll
        for (int i = 0; i < 4; i++) { as0[i] = 0.f; as1[i] = 0.f; ad0[i] = 0.f; ad1[i] = 0.f; }

#pragma unroll 4
        for (int o = 0; o < FOUT; o++) {
            size_t aoff = ((size_t)hh * FOUT + o) * DD;
            float sv0 = a_src[aoff + tx];
            float sv1 = a_src[aoff + tx + 32];
            float dv0 = a_dst[aoff + tx];
            float dv1 = a_dst[aoff + tx + 32];
#pragma unroll
            for (int i = 0; i < 4; i++) {
                float hv = hpL[i * 8 + ty][o];
                as0[i] += hv * sv0; as1[i] += hv * sv1;
                ad0[i] += hv * dv0; ad1[i] += hv * dv1;
            }
        }
#pragma unroll
        for (int i = 0; i < 4; i++) {
            int r = i * 8 + ty;
            size_t base = (bh * NN + n0 + r) * DD;
            unsigned short h0, h1;
            h0 = f2bf(as0[i]); asHg[base + tx]      = h0; asLg[base + tx]      = f2bf(as0[i] - bf2f(h0));
            h1 = f2bf(as1[i]); asHg[base + tx + 32] = h1; asLg[base + tx + 32] = f2bf(as1[i] - bf2f(h1));
            h0 = f2bf(ad0[i]); adHg[base + tx]      = h0; adLg[base + tx]      = f2bf(ad0[i] - bf2f(h0));
            h1 = f2bf(ad1[i]); adHg[base + tx + 32] = h1; adLg[base + tx + 32] = f2bf(ad1[i] - bf2f(h1));
        }

        // fragment-packed bf16 h' : hpP[bh][n0/32][o][r]
        {
            int o = t & 127, half = t >> 7;
            size_t dst = ((bh * (NN / 32) + (n0 >> 5)) * FOUT + o) * 32 + half * 16;
            short8 v0, v1;
#pragma unroll
            for (int k = 0; k < 8; k++) v0[k] = (short)f2bf(hpL[half * 16 + k][o]);
#pragma unroll
            for (int k = 0; k < 8; k++) v1[k] = (short)f2bf(hpL[half * 16 + 8 + k][o]);
            *reinterpret_cast<short8*>(&hpPg[dst])     = v0;
            *reinterpret_cast<short8*>(&hpPg[dst + 8]) = v1;
        }
    }

#pragma unroll
    for (int i = 0; i < 4; i++) {
        int r = i * 8 + ty;
        size_t rowoff = ((size_t)b * NN + n0 + r) * FOUT;
#pragma unroll
        for (int j = 0; j < 4; j++) {
            hpsum[rowoff + j * 32 + tx] = sum_acc[i][j];
        }
    }
}

// ---------------- Kernel 2: swapped scores + online e-cache (bf16) -> attn + PV ----------------
// grid: BB*(NN/RT2) = 1024 blocks, 256 threads (4 waves). LDS 8.7 KB. VGPR cap ~170.
__global__ __launch_bounds__(256, 3) void gat_k2(
    const float* __restrict__ mask,   // [B,1,N,N]
    const float* __restrict__ bias,   // [FOUT]
    const unsigned short* __restrict__ asHg,
    const unsigned short* __restrict__ asLg,
    const unsigned short* __restrict__ adHg,
    const unsigned short* __restrict__ adLg,
    const unsigned short* __restrict__ hpPg,  // [B*H][N/32][FOUT][32]
    const float* __restrict__ hpsum,  // [B,N,FOUT]
    float* __restrict__ out,          // [B,N,FOUT]
    float* __restrict__ attn)         // [B,H,N,N]
{
    __shared__ __align__(16) unsigned char smem[8192 + 512];
    unsigned short* pBs0 = reinterpret_cast<unsigned short*>(smem);          // 4 KB
    unsigned short* pBs1 = reinterpret_cast<unsigned short*>(smem + 4096);   // 4 KB
    float2*         red  = reinterpret_cast<float2*>(smem + 8192);           // 64 float2
    float*          outL = reinterpret_cast<float*>(smem);                   // epilogue alias, 8 KB

    const int t  = threadIdx.x;
    const int l  = t & 63;
    const int w  = t >> 6;
    const int li = l & 15;
    const int g  = l >> 4;
    const int colb = w * 32;

    // XCD-aware bijective swizzle (1024 % 8 == 0)
    const int lb = (blockIdx.x & 7) * 128 + (blockIdx.x >> 3);
    const int b  = lb >> 6;
    const int n0 = (lb & 63) * RT2;

    f32x4 oacc[2];
    oacc[0] = f32x4{0.f, 0.f, 0.f, 0.f};
    oacc[1] = f32x4{0.f, 0.f, 0.f, 0.f};

    for (int hh = 0; hh < HH; hh++) {
        const size_t bh = (size_t)b * HH + hh;

        // as fragments (Y operand of swapped MFMA): row n0+li, k = ks*32 + g*8
        short8 aH[2], aL[2];
#pragma unroll
        for (int ks = 0; ks < 2; ks++) {
            size_t src = (bh * NN + n0 + li) * DD + ks * 32 + g * 8;
            aH[ks] = *reinterpret_cast<const short8*>(&asHg[src]);
            aL[ks] = *reinterpret_cast<const short8*>(&asLg[src]);
        }

        const unsigned short* adHb = adHg + bh * NN * DD;
        const unsigned short* adLb = adLg + bh * NN * DD;

        // ===== pass A: swapped scores, online (m,l), e packed to bf16 =====
        // lane (li,g) owns S[row n0+li][c = ct*CT + colb + cf*16 + g*4 + q]
        float m = -3.0e38f, lsum = 0.f;
        float mL[8];
        unsigned pk[8][2][2];   // [ct][cf][pair] bf16x2 of e
#pragma unroll
        for (int ct = 0; ct < 8; ct++) {
            float sv[2][4];
#pragma unroll
            for (int cf = 0; cf < 2; cf++) {
                short8 xH[2], xL[2];
#pragma unroll
                for (int ks = 0; ks < 2; ks++) {
                    size_t off = (size_t)(ct * CT + colb + cf * 16 + li) * DD + ks * 32 + g * 8;
                    xH[ks] = *reinterpret_cast<const short8*>(&adHb[off]);
                    xL[ks] = *reinterpret_cast<const short8*>(&adLb[off]);
                }
                f32x4 s = f32x4{0.f, 0.f, 0.f, 0.f};
                __builtin_amdgcn_s_setprio(1);
#pragma unroll
                for (int ks = 0; ks < 2; ks++) {
                    s = MFMA(xH[ks], aH[ks], s);
                    s = MFMA(xH[ks], aL[ks], s);
                    s = MFMA(xL[ks], aH[ks], s);
                }
                __builtin_amdgcn_s_setprio(0);
#pragma unroll
                for (int q = 0; q < 4; q++) {
                    float v = s[q];
                    sv[cf][q] = v > 0.f ? v : NEG * v;
                }
            }
            // tile max, rescale l, exp, pack
            float tm = sv[0][0];
#pragma unroll
            for (int cf = 0; cf < 2; cf++)
#pragma unroll
                for (int q = 0; q < 4; q++) tm = fmaxf(tm, sv[cf][q]);
            float nm = fmaxf(m, tm);
            lsum *= __expf(m - nm);
            m = nm;
            mL[ct] = nm;
#pragma unroll
            for (int cf = 0; cf < 2; cf++) {
                float e0 = __expf(sv[cf][0] - nm);
                float e1 = __expf(sv[cf][1] - nm);
                float e2 = __expf(sv[cf][2] - nm);
                float e3 = __expf(sv[cf][3] - nm);
                lsum += (e0 + e1) + (e2 + e3);
                pk[ct][cf][0] = pack2bf(e0, e1);
                pk[ct][cf][1] = pack2bf(e2, e3);
            }
        }

        // ===== reduce (m,l): xor 16/32 across g, LDS across waves =====
#pragma unroll
        for (int msk = 16; msk <= 32; msk <<= 1) {
            float om = __shfl_xor(m, msk);
            float ol = __shfl_xor(lsum, msk);
            float nm = fmaxf(m, om);
            lsum = lsum * __expf(m - nm) + ol * __expf(om - nm);
            m = nm;
        }
        __syncthreads();   // red region free
        if (g == 0) red[w * 16 + li] = make_float2(m, lsum);
        __syncthreads();
        float mf, linv;
        {
            float2 r0 = red[li], r1 = red[16 + li], r2 = red[32 + li], r3 = red[48 + li];
            mf = fmaxf(fmaxf(r0.x, r1.x), fmaxf(r2.x, r3.x));
            float ls = r0.y * __expf(r0.x - mf) + r1.y * __expf(r1.x - mf)
                     + r2.y * __expf(r2.x - mf) + r3.y * __expf(r3.x - mf);
            linv = 1.0f / ls;
        }

        // ===== pass B: p = e*corr*mask -> attn float4 -> pB -> PV =====
        const unsigned short* hpbase = hpPg + bh * (size_t)(NN / 32) * FOUT * 32;
#pragma unroll
        for (int ct = 0; ct < 8; ct++) {
            const float corr = __expf(mL[ct] - mf) * linv;
            unsigned short* pB = (ct & 1) ? pBs1 : pBs0;
#pragma unroll
            for (int cf = 0; cf < 2; cf++) {
                int c = ct * CT + colb + cf * 16 + g * 4;
                float4 mv = *reinterpret_cast<const float4*>(
                    &mask[((size_t)b * NN + n0 + li) * NN + c]);
                float p0 = bf2f((unsigned short)(pk[ct][cf][0] & 0xffff)) * corr * mv.x;
                float p1 = bf2f((unsigned short)(pk[ct][cf][0] >> 16))    * corr * mv.y;
                float p2 = bf2f((unsigned short)(pk[ct][cf][1] & 0xffff)) * corr * mv.z;
                float p3 = bf2f((unsigned short)(pk[ct][cf][1] >> 16))    * corr * mv.w;
                float4 av; av.x = p0; av.y = p1; av.z = p2; av.w = p3;
                *reinterpret_cast<float4*>(
                    &attn[(bh * NN + n0 + li) * NN + c]) = av;
                // pB[row=li][c_local], swizzled; 4 consecutive shorts stay contiguous
                int c0 = colb + cf * 16 + g * 4;
                uint2 pw;
                pw.x = pack2bf(p0, p1);
                pw.y = pack2bf(p2, p3);
                *reinterpret_cast<uint2*>(&pB[li * 128 + (c0 ^ (li * 8))]) = pw;
            }

            // T14: pre-issue half the PV B-operand loads before the barrier
            const unsigned short* hpb = hpbase + (size_t)ct * 4 * FOUT * 32;
            short8 hbv[2][2];
#pragma unroll
            for (int kc = 0; kc < 2; kc++) {
                hbv[kc][0] = *reinterpret_cast<const short8*>(
                    &hpb[((size_t)kc * FOUT + colb + li) * 32 + g * 8]);
                hbv[kc][1] = *reinterpret_cast<const short8*>(
                    &hpb[((size_t)kc * FOUT + colb + 16 + li) * 32 + g * 8]);
            }
            asm volatile("s_waitcnt lgkmcnt(0)\n\ts_barrier" ::: "memory");

#pragma unroll
            for (int kc = 0; kc < 2; kc++) {
                int k = kc * 32 + g * 8;
                short8 pa = *reinterpret_cast<const short8*>(&pB[li * 128 + (k ^ (li * 8))]);
                __builtin_amdgcn_s_setprio(1);
                oacc[0] = MFMA(pa, hbv[kc][0], oacc[0]);
                oacc[1] = MFMA(pa, hbv[kc][1], oacc[1]);
                __builtin_amdgcn_s_setprio(0);
            }
#pragma unroll
            for (int kc = 2; kc < 4; kc++) {
                int k = kc * 32 + g * 8;
                short8 pa = *reinterpret_cast<const short8*>(&pB[li * 128 + (k ^ (li * 8))]);
                short8 h0 = *reinterpret_cast<const short8*>(
                    &hpb[((size_t)kc * FOUT + colb + li) * 32 + g * 8]);
                short8 h1 = *reinterpret_cast<const short8*>(
                    &hpb[((size_t)kc * FOUT + colb + 16 + li) * 32 + g * 8]);
                __builtin_amdgcn_s_setprio(1);
                oacc[0] = MFMA(pa, h0, oacc[0]);
                oacc[1] = MFMA(pa, h1, oacc[1]);
                __builtin_amdgcn_s_setprio(0);
            }
        }
    }

    // epilogue: stage oacc -> LDS (f32 16x128), then coalesced out write
    __syncthreads();
#pragma unroll
    for (int of = 0; of < 2; of++)
#pragma unroll
        for (int q = 0; q < 4; q++) {
            int row = g * 4 + q;
            int col = colb + of * 16 + li;
            outL[row * 128 + col] = oacc[of][q];
        }
    __syncthreads();
    {
        int row = t >> 4, cb = (t & 15) * 8;
        size_t obase = ((size_t)b * NN + n0 + row) * FOUT + cb;
#pragma unroll
        for (int k4 = 0; k4 < 2; k4++) {
            float4 v  = *reinterpret_cast<float4*>(&outL[row * 128 + cb + k4 * 4]);
            float4 bs = *reinterpret_cast<const float4*>(&bias[cb + k4 * 4]);
            float4 hs = *reinterpret_cast<const float4*>(&hpsum[obase + k4 * 4]);
            v.x += bs.x + hs.x; v.y += bs.y + hs.y; v.z += bs.z + hs.z; v.w += bs.w + hs.w;
            *reinterpret_cast<float4*>(&out[obase + k4 * 4]) = v;
        }
    }
}

extern "C" void kernel_launch(void* const* d_in, const int* in_sizes, int n_in,
                              void* d_out, int out_size, void* d_ws, size_t ws_size,
                              hipStream_t stream) {
    const float* h      = (const float*)d_in[0];
    const float* mask   = (const float*)d_in[1];
    const float* w      = (const float*)d_in[2];
    const float* a_src  = (const float*)d_in[3];
    const float* a_dst  = (const float*)d_in[4];
    const float* bias   = (const float*)d_in[5];

    float* out  = (float*)d_out;                          // [B,N,FOUT]
    float* attn = out + (size_t)BB * NN * FOUT;           // [B,H,N,N]

    const size_t NASD = (size_t)BB * HH * NN * DD;        // 4M elems
    unsigned short* asHg = (unsigned short*)d_ws;
    unsigned short* asLg = asHg + NASD;
    unsigned short* adHg = asLg + NASD;
    unsigned short* adLg = adHg + NASD;
    unsigned short* hpPg = adLg + NASD;                   // B*H*FOUT*N = 8M elems
    float* hpsum = (float*)(hpPg + (size_t)BB * HH * FOUT * NN);

    dim3 block(256);
    gat_k1<<<dim3(BB * (NN / RT)),  block, 0, stream>>>(h, w, a_src, a_dst, asHg, asLg, adHg, adLg, hpPg, hpsum);
    gat_k2<<<dim3(BB * (NN / RT2)), block, 0, stream>>>(mask, bias, asHg, asLg, adHg, adLg, hpPg, hpsum, out, attn);
}